// Round 6
// baseline (401.886 us; speedup 1.0000x reference)
//
#include <hip/hip_runtime.h>
#include <stdint.h>

#define T_STEPS 256
#define F_IN 64
#define L2E 1.44269504f

typedef __bf16 bf16x8 __attribute__((ext_vector_type(8)));
typedef float f32x4 __attribute__((ext_vector_type(4)));
typedef uint32_t u32;
typedef uint32_t u32x2 __attribute__((ext_vector_type(2)));
typedef uint32_t u32x4 __attribute__((ext_vector_type(4)));

#define GLDS16(gp, lp)                                                         \
    __builtin_amdgcn_global_load_lds(                                          \
        (const __attribute__((address_space(1))) unsigned int*)(gp),           \
        (__attribute__((address_space(3))) unsigned int*)(lp), 16, 0, 0)

static __device__ __forceinline__ u32 pk2(float lo, float hi) {
    unsigned short a = __builtin_bit_cast(unsigned short, (__bf16)lo);
    unsigned short b = __builtin_bit_cast(unsigned short, (__bf16)hi);
    return (u32)a | ((u32)b << 16);
}

// One wave owns TWO independent 16-row tiles (A,B), both full recurrences,
// interleaved in one instruction stream. NO barriers, no cross-wave traffic.
// Transposed MFMA: gates^T[128][16] = W^T[128][96] @ [x|h]^T[96][16]
// A-frag (W^T): elem j of lane l -> W^T[gate=q*16+(l&15)][k=(l>>4)*8+j]
// B-frag (x/h): elem j of lane l -> [x|h]^T[k=(l>>4)*8+j][batch=l&15]
// D          : elem r of lane l -> gates^T[gate=q*16+(l>>4)*4+r][batch=l&15]
// h round-trip in per-wave LDS: write hb[cl][u] (2x ds_write_b64),
// read back as B-frag (1x ds_read_b128).
__global__ __launch_bounds__(128, 1)
void lstm_fused(const float* __restrict__ x,
                const float* __restrict__ Wl,   // [96][128]
                const float* __restrict__ bl,   // [128]
                const float* __restrict__ Wd,   // [32]
                const float* __restrict__ bd,   // [1]
                float* __restrict__ out)        // [B]
{
    __shared__ __align__(16) float  xs[2][3][2][1024];  // [wave][slot][tile][] 48 KB
    __shared__ __align__(16) __bf16 hb[2][2][16][32];   // [wave][tile][batch][unit] 4 KB

    const int lane = threadIdx.x & 63;
    const int wid  = threadIdx.x >> 6;
    const int cl   = lane & 15;
    const int g4   = lane >> 4;
    const int rowBase = blockIdx.x * 64 + wid * 32;     // tile A rows; tile B = +16

    // ---- all 24 W^T A-fragments (shared by both tiles) ----
    bf16x8 wfrag[3][8];
#pragma unroll
    for (int kc = 0; kc < 3; ++kc) {
#pragma unroll
        for (int qi = 0; qi < 8; ++qi) {
            bf16x8 v;
#pragma unroll
            for (int j = 0; j < 8; ++j)
                v[j] = (__bf16)Wl[(kc * 32 + g4 * 8 + j) * 128 + qi * 16 + cl];
            wfrag[kc][qi] = v;
        }
    }

    // ---- folded bias constants; lane's cells u = uh*16 + g4*4 + r (both halves) ----
    float KI[2][4], KJ[2][4], KF[2][4], KO[2][4];
#pragma unroll
    for (int uh = 0; uh < 2; ++uh) {
        const int u0 = uh * 16 + g4 * 4;
#pragma unroll
        for (int r = 0; r < 4; ++r) {
            KI[uh][r] = -L2E        *  bl[      u0 + r];
            KJ[uh][r] = -2.0f * L2E *  bl[ 32 + u0 + r];
            KF[uh][r] = -L2E        * (bl[ 64 + u0 + r] + 1.0f);
            KO[uh][r] = -L2E        *  bl[ 96 + u0 + r];
        }
    }
    const float bd0 = bd[0];
    const f32x4 wd0 = *(const f32x4*)(Wd + g4 * 8);
    const f32x4 wd1 = *(const f32x4*)(Wd + g4 * 8 + 4);

    // per-lane pre-swizzled global bases (row = lane>>2, chunk (lane&3)^((lane>>3)&3))
    const float* gbA = x + (size_t)(rowBase + (lane >> 2)) * (size_t)(T_STEPS * F_IN)
                         + (size_t)(((lane & 3) ^ ((lane >> 3) & 3)) * 4);
    const float* gbB = gbA + (size_t)16 * (size_t)(T_STEPS * F_IN);

    // h0 = 0 for both tiles (each lane zeroes exactly its read region)
    *reinterpret_cast<u32x4*>(&hb[wid][0][cl][g4 * 8]) = u32x4{0u, 0u, 0u, 0u};
    *reinterpret_cast<u32x4*>(&hb[wid][1][cl][g4 * 8]) = u32x4{0u, 0u, 0u, 0u};

    asm volatile("s_waitcnt vmcnt(0)" ::: "memory");    // drain setup loads: exact counting
    __builtin_amdgcn_sched_barrier(0);

#define STAGE(TT, SP) do {                                                     \
    const float* gpA = gbA + (TT) * F_IN;                                      \
    GLDS16(gpA,      &xs[wid][SP][0][0]);                                      \
    GLDS16(gpA + 16, &xs[wid][SP][0][256]);                                    \
    GLDS16(gpA + 32, &xs[wid][SP][0][512]);                                    \
    GLDS16(gpA + 48, &xs[wid][SP][0][768]);                                    \
    const float* gpB = gbB + (TT) * F_IN;                                      \
    GLDS16(gpB,      &xs[wid][SP][1][0]);                                      \
    GLDS16(gpB + 16, &xs[wid][SP][1][256]);                                    \
    GLDS16(gpB + 32, &xs[wid][SP][1][512]);                                    \
    GLDS16(gpB + 48, &xs[wid][SP][1][768]);                                    \
} while (0)

    STAGE(0, 0);
    STAGE(1, 1);

    const int swz = (cl >> 1) & 3;
    const int c0  = ((g4 & 1) * 2)     ^ swz;
    const int c1  = ((g4 & 1) * 2 + 1) ^ swz;
    const int kA  = (g4 >> 1) * 256 + cl * 16;
    const int kB  = kA + 512;
    const f32x4 z4 = {0.f, 0.f, 0.f, 0.f};

    float csA[2][4] = {{0.f,0.f,0.f,0.f},{0.f,0.f,0.f,0.f}};
    float csB[2][4] = {{0.f,0.f,0.f,0.f},{0.f,0.f,0.f,0.f}};

    // One tile's full step: read x-slot + h, 24 MFMAs, 8 cells/lane, publish h.
#define TSTEP(G, SL, CS) do {                                                  \
    const float* sl = &xs[wid][SL][G][0];                                      \
    f32x4 xr0 = *(const f32x4*)(sl + kA + c0 * 4);                             \
    f32x4 xr1 = *(const f32x4*)(sl + kA + c1 * 4);                             \
    f32x4 xr2 = *(const f32x4*)(sl + kB + c0 * 4);                             \
    f32x4 xr3 = *(const f32x4*)(sl + kB + c1 * 4);                             \
    bf16x8 ah = *reinterpret_cast<const bf16x8*>(&hb[wid][G][cl][g4 * 8]);     \
    bf16x8 ax0, ax1;                                                           \
    _Pragma("unroll")                                                          \
    for (int j = 0; j < 4; ++j) {                                              \
        ax0[j]     = (__bf16)xr0[j];                                           \
        ax0[4 + j] = (__bf16)xr1[j];                                           \
        ax1[j]     = (__bf16)xr2[j];                                           \
        ax1[4 + j] = (__bf16)xr3[j];                                           \
    }                                                                          \
    f32x4 acc[8];                                                              \
    _Pragma("unroll")                                                          \
    for (int qi = 0; qi < 8; ++qi) {                                           \
        f32x4 a = __builtin_amdgcn_mfma_f32_16x16x32_bf16(wfrag[0][qi], ax0, z4, 0, 0, 0); \
        a = __builtin_amdgcn_mfma_f32_16x16x32_bf16(wfrag[1][qi], ax1, a, 0, 0, 0);        \
        a = __builtin_amdgcn_mfma_f32_16x16x32_bf16(wfrag[2][qi], ah,  a, 0, 0, 0);        \
        acc[qi] = a;                                                           \
    }                                                                          \
    float hh[2][4];                                                            \
    _Pragma("unroll")                                                          \
    for (int uh = 0; uh < 2; ++uh) {                                           \
        _Pragma("unroll")                                                      \
        for (int r = 0; r < 4; ++r) {                                          \
            float I  = __builtin_amdgcn_exp2f(__builtin_fmaf(acc[0+uh][r], -L2E,        KI[uh][r])); \
            float J  = __builtin_amdgcn_exp2f(__builtin_fmaf(acc[2+uh][r], -2.0f * L2E, KJ[uh][r])); \
            float P  = (1.0f - J) * __builtin_amdgcn_rcpf((1.0f + I) * (1.0f + J));      \
            float Fv = __builtin_amdgcn_exp2f(__builtin_fmaf(acc[4+uh][r], -L2E,        KF[uh][r])); \
            float S  = __builtin_amdgcn_rcpf(1.0f + Fv);                       \
            float cn = __builtin_fmaf(CS[uh][r], S, P);                        \
            float C  = __builtin_amdgcn_exp2f(-2.0f * L2E * cn);               \
            float O  = __builtin_amdgcn_exp2f(__builtin_fmaf(acc[6+uh][r], -L2E, KO[uh][r])); \
            hh[uh][r] = (1.0f - C) * __builtin_amdgcn_rcpf((1.0f + C) * (1.0f + O));     \
            CS[uh][r] = cn;                                                    \
        }                                                                      \
    }                                                                          \
    *reinterpret_cast<u32x2*>(&hb[wid][G][cl][g4 * 4]) =                       \
        u32x2{pk2(hh[0][0], hh[0][1]), pk2(hh[0][2], hh[0][3])};               \
    *reinterpret_cast<u32x2*>(&hb[wid][G][cl][16 + g4 * 4]) =                  \
        u32x2{pk2(hh[1][0], hh[1][1]), pk2(hh[1][2], hh[1][3])};               \
} while (0)

    // One iteration = both tiles' step TT. slot SL = TT%3, stage slot SP = (TT+2)%3.
#define ITER(TT, SL, SP, WN) do {                                              \
    asm volatile("s_waitcnt vmcnt(" #WN ")" ::: "memory");                     \
    __builtin_amdgcn_sched_barrier(0);                                         \
    if ((TT) + 2 < T_STEPS) STAGE((TT) + 2, SP);                               \
    TSTEP(0, SL, csA);                                                         \
    TSTEP(1, SL, csB);                                                         \
} while (0)

    for (int t = 0; t < 252; t += 3) {
        ITER(t,     0, 2, 8);
        ITER(t + 1, 1, 0, 8);
        ITER(t + 2, 2, 1, 8);
    }
    ITER(252, 0, 2, 8);
    ITER(253, 1, 0, 8);
    ITER(254, 2, 1, 8);   // stage skipped (256 >= T), 8 remain in flight (slot for 255)
    ITER(255, 0, 2, 0);
#undef ITER
#undef TSTEP
#undef STAGE

    // ---- epilogue: out[b] = ELU(sum_u h[u]*Wd[u] + bd) for both tiles ----
#pragma unroll
    for (int G = 0; G < 2; ++G) {
        bf16x8 hfin = *reinterpret_cast<const bf16x8*>(&hb[wid][G][cl][g4 * 8]);
        float v = 0.f;
#pragma unroll
        for (int j = 0; j < 4; ++j) {
            v = __builtin_fmaf((float)hfin[j],     wd0[j], v);
            v = __builtin_fmaf((float)hfin[4 + j], wd1[j], v);
        }
        v += __shfl_xor(v, 16, 64);
        v += __shfl_xor(v, 32, 64);
        if (lane < 16) {
            float z = v + bd0;
            out[rowBase + G * 16 + lane] = z > 0.f ? z : (__expf(z) - 1.0f);
        }
    }
}

extern "C" void kernel_launch(void* const* d_in, const int* in_sizes, int n_in,
                              void* d_out, int out_size, void* d_ws, size_t ws_size,
                              hipStream_t stream) {
    const float* x  = (const float*)d_in[0];
    const float* Wl = (const float*)d_in[1];
    const float* bl = (const float*)d_in[2];
    const float* Wd = (const float*)d_in[3];
    const float* bd = (const float*)d_in[4];
    float* out = (float*)d_out;

    const int rows = out_size;              // B = 16384
    const int grid = (rows + 63) / 64;      // 64 rows per 128-thread block (2 waves x 2 tiles x 16)
    hipLaunchKernelGGL(lstm_fused, dim3(grid), dim3(128), 0, stream,
                       x, Wl, bl, Wd, bd, out);
}

// Round 7
// 249.932 us; speedup vs baseline: 1.6080x; 1.6080x over previous
//
#include <hip/hip_runtime.h>
#include <stdint.h>

#define T_STEPS 256
#define F_IN 64
#define L2E 1.44269504f

typedef __bf16 bf16x8 __attribute__((ext_vector_type(8)));
typedef float f32x4 __attribute__((ext_vector_type(4)));
typedef uint32_t u32;
typedef uint32_t u32x2 __attribute__((ext_vector_type(2)));
typedef uint32_t u32x4 __attribute__((ext_vector_type(4)));

#define GLDS16(gp, lp)                                                         \
    __builtin_amdgcn_global_load_lds(                                          \
        (const __attribute__((address_space(1))) unsigned int*)(gp),           \
        (__attribute__((address_space(3))) unsigned int*)(lp), 16, 0, 0)

static __device__ __forceinline__ u32 pk2(float lo, float hi) {
    unsigned short a = __builtin_bit_cast(unsigned short, (__bf16)lo);
    unsigned short b = __builtin_bit_cast(unsigned short, (__bf16)hi);
    return (u32)a | ((u32)b << 16);
}

// R4 structure (2 waves per 16-row tile, unit-split, dbuf h, 1 barrier/step) +
//  (1) per-block phase stagger so co-resident waves don't stall in lockstep,
//  (2) activation scales folded into W frags, biases via MFMA C-operand,
//      merged-rcp cell with state c' = -2*log2e*c  (7 trans / 14 VALU per cell).
// Transposed MFMA: gates^T[g][16] = (S.W^T)[g][96] @ [x|h]^T[96][16]
// A-frag: elem j of lane l -> W'[gate=q*16+(l&15)][k=(l>>4)*8+j]
// B-frag: elem j of lane l -> [x|h]^T[k=(l>>4)*8+j][batch=l&15]
// D     : elem r of lane l -> gates'[gate=q*16+(l>>4)*4+r][batch=l&15]
__global__ __launch_bounds__(128, 2)
void lstm_fused(const float* __restrict__ x,
                const float* __restrict__ Wl,   // [96][128]
                const float* __restrict__ bl,   // [128]
                const float* __restrict__ Wd,   // [32]
                const float* __restrict__ bd,   // [1]
                float* __restrict__ out)        // [B]
{
    __shared__ __align__(16) float  xs[4][1024];   // 16 KB x ring
    __shared__ __align__(16) __bf16 hf[2][64][8];  // h in MFMA B-frag layout, dbuf

    const int lane = threadIdx.x & 63;
    const int wid  = threadIdx.x >> 6;             // unit-half owner
    const int cl   = lane & 15;
    const int g4   = lane >> 4;
    const int rowBase = blockIdx.x * 16;

    // gate-type scale per qi (q = 2*qi+wid: qi=0 i, 1 j, 2 f, 3 o)
    const float gsc[4] = {-L2E, -2.0f * L2E, -L2E, -L2E};

    // ---- this wave's 12 pre-scaled W^T A-fragments ----
    bf16x8 wfrag[3][4];
#pragma unroll
    for (int kc = 0; kc < 3; ++kc) {
#pragma unroll
        for (int qi = 0; qi < 4; ++qi) {
            bf16x8 v;
#pragma unroll
            for (int j = 0; j < 8; ++j)
                v[j] = (__bf16)(gsc[qi] * Wl[(kc * 32 + g4 * 8 + j) * 128 + (2 * qi + wid) * 16 + cl]);
            wfrag[kc][qi] = v;
        }
    }

    // ---- pre-scaled bias as MFMA C-init: biasf[qi][r] = gsc*(bl[gate]+ (f?1:0)) ----
    f32x4 biasf[4];
#pragma unroll
    for (int qi = 0; qi < 4; ++qi) {
#pragma unroll
        for (int r = 0; r < 4; ++r) {
            const int gate = (2 * qi + wid) * 16 + g4 * 4 + r;
            biasf[qi][r] = gsc[qi] * (bl[gate] + (qi == 2 ? 1.0f : 0.0f));
        }
    }
    const float bd0 = bd[0];
    const f32x4 wdA = *(const f32x4*)(Wd + g4 * 8);
    const f32x4 wdB = *(const f32x4*)(Wd + g4 * 8 + 4);

    // per-lane pre-swizzled global base
    const float* gbase = x + (size_t)(rowBase + (lane >> 2)) * (size_t)(T_STEPS * F_IN)
                           + (size_t)(((lane & 3) ^ ((lane >> 3) & 3)) * 4);

    // h0 = 0
    if (threadIdx.x < 64)
        *reinterpret_cast<u32x4*>(&hf[0][threadIdx.x][0]) = u32x4{0u, 0u, 0u, 0u};

    // ---- phase stagger: 4 quarter-step phases across co-resident blocks ----
    {
        const int phase = (blockIdx.x >> 8) & 3;
#pragma unroll 1
        for (int i = 0; i < phase; ++i) __builtin_amdgcn_s_sleep(10);  // ~640 cyc each
    }

    asm volatile("s_waitcnt vmcnt(0)" ::: "memory");   // drain setup loads: exact counting
    __builtin_amdgcn_sched_barrier(0);

    // prologue prefetch: slots 0..2, 2 loads/wave/slot
#pragma unroll
    for (int s = 0; s < 3; ++s) {
        const float* gp = gbase + s * F_IN + wid * 32;
        GLDS16(gp,      &xs[s][wid * 512]);
        GLDS16(gp + 16, &xs[s][wid * 512 + 256]);
    }

    asm volatile("s_waitcnt vmcnt(4) lgkmcnt(0)" ::: "memory");
    __builtin_amdgcn_sched_barrier(0);
    __builtin_amdgcn_s_barrier();
    __builtin_amdgcn_sched_barrier(0);

    const int swz = (cl >> 1) & 3;
    const int c0  = ((g4 & 1) * 2)     ^ swz;
    const int c1  = ((g4 & 1) * 2 + 1) ^ swz;
    const int kA  = (g4 >> 1) * 256 + cl * 16;
    const int kB  = kA + 512;

    // h-publish slot (unchanged from R4)
    const int tT = (2 * wid + (g4 >> 1)) * 16 + cl;
    const int e0 = (g4 & 1) * 4;

    float c_st[4] = {0.f, 0.f, 0.f, 0.f};   // state c' = -2*L2E*c

#define STEP(TT) do {                                                          \
    const int par = (TT) & 1;                                                  \
    const float* sl = &xs[(TT) & 3][0];                                        \
    f32x4 xr0 = *(const f32x4*)(sl + kA + c0 * 4);                             \
    f32x4 xr1 = *(const f32x4*)(sl + kA + c1 * 4);                             \
    f32x4 xr2 = *(const f32x4*)(sl + kB + c0 * 4);                             \
    f32x4 xr3 = *(const f32x4*)(sl + kB + c1 * 4);                             \
    bf16x8 ah = *reinterpret_cast<const bf16x8*>(&hf[par][lane][0]);           \
    const int tpf = ((TT) + 3 < T_STEPS) ? (TT) + 3 : T_STEPS - 1;             \
    const float* gp = gbase + tpf * F_IN + wid * 32;                           \
    GLDS16(gp,      &xs[((TT)+3) & 3][wid * 512]);                             \
    GLDS16(gp + 16, &xs[((TT)+3) & 3][wid * 512 + 256]);                       \
    bf16x8 ax0, ax1;                                                           \
    _Pragma("unroll")                                                          \
    for (int j = 0; j < 4; ++j) {                                              \
        ax0[j]     = (__bf16)xr0[j];                                           \
        ax0[4 + j] = (__bf16)xr1[j];                                           \
        ax1[j]     = (__bf16)xr2[j];                                           \
        ax1[4 + j] = (__bf16)xr3[j];                                           \
    }                                                                          \
    f32x4 acc[4];                                                              \
    __builtin_amdgcn_s_setprio(1);                                             \
    _Pragma("unroll")                                                          \
    for (int qi = 0; qi < 4; ++qi) {                                           \
        f32x4 a = __builtin_amdgcn_mfma_f32_16x16x32_bf16(wfrag[0][qi], ax0, biasf[qi], 0, 0, 0); \
        a = __builtin_amdgcn_mfma_f32_16x16x32_bf16(wfrag[1][qi], ax1, a, 0, 0, 0);               \
        a = __builtin_amdgcn_mfma_f32_16x16x32_bf16(wfrag[2][qi], ah,  a, 0, 0, 0);               \
        acc[qi] = a;                                                           \
    }                                                                          \
    __builtin_amdgcn_s_setprio(0);                                             \
    float hh[4];                                                               \
    _Pragma("unroll")                                                          \
    for (int r = 0; r < 4; ++r) {                                              \
        float I  = __builtin_amdgcn_exp2f(acc[0][r]);                          \
        float J  = __builtin_amdgcn_exp2f(acc[1][r]);                          \
        float Fv = __builtin_amdgcn_exp2f(acc[2][r]);                          \
        float O  = __builtin_amdgcn_exp2f(acc[3][r]);                          \
        float t1 = 1.0f + I;                                                   \
        float t2 = 1.0f + J;                                                   \
        float t3 = t1 * t2;                                                    \
        float u  = 1.0f + Fv;                                                  \
        float np = __builtin_fmaf(J, 2.0f * L2E, -2.0f * L2E);                 \
        float r1 = __builtin_amdgcn_rcpf(t3 * u);                              \
        float num = __builtin_fmaf(c_st[r], t3, np * u);                       \
        float cp = num * r1;                                                   \
        float C  = __builtin_amdgcn_exp2f(cp);                                 \
        float r2 = __builtin_amdgcn_rcpf((1.0f + C) * (1.0f + O));             \
        hh[r] = (1.0f - C) * r2;                                               \
        c_st[r] = cp;                                                          \
    }                                                                          \
    *reinterpret_cast<u32x2*>(&hf[par ^ 1][tT][e0]) =                          \
        u32x2{pk2(hh[0], hh[1]), pk2(hh[2], hh[3])};                           \
    asm volatile("s_waitcnt vmcnt(4) lgkmcnt(0)" ::: "memory");                \
    __builtin_amdgcn_sched_barrier(0);                                         \
    __builtin_amdgcn_s_barrier();                                              \
    __builtin_amdgcn_sched_barrier(0);                                         \
} while (0)

    for (int t = 0; t < T_STEPS; t += 4) {
        STEP(t);
        STEP(t + 1);
        STEP(t + 2);
        STEP(t + 3);
    }
#undef STEP

    // ---- epilogue: out[b] = ELU(sum_u h[u]*Wd[u] + bd) ----
    if (wid == 0) {
        bf16x8 hfin = *reinterpret_cast<const bf16x8*>(&hf[0][lane][0]);
        float v = 0.f;
#pragma unroll
        for (int j = 0; j < 4; ++j) {
            v = __builtin_fmaf((float)hfin[j],     wdA[j], v);
            v = __builtin_fmaf((float)hfin[4 + j], wdB[j], v);
        }
        v += __shfl_xor(v, 16, 64);
        v += __shfl_xor(v, 32, 64);
        if (lane < 16) {
            float z = v + bd0;
            out[rowBase + lane] = z > 0.f ? z : (__expf(z) - 1.0f);
        }
    }
}

extern "C" void kernel_launch(void* const* d_in, const int* in_sizes, int n_in,
                              void* d_out, int out_size, void* d_ws, size_t ws_size,
                              hipStream_t stream) {
    const float* x  = (const float*)d_in[0];
    const float* Wl = (const float*)d_in[1];
    const float* bl = (const float*)d_in[2];
    const float* Wd = (const float*)d_in[3];
    const float* bd = (const float*)d_in[4];
    float* out = (float*)d_out;

    const int rows = out_size;              // B = 16384
    const int grid = (rows + 15) / 16;      // 16 rows per 128-thread block (2 waves/tile)
    hipLaunchKernelGGL(lstm_fused, dim3(grid), dim3(128), 0, stream,
                       x, Wl, bl, Wd, bd, out);
}

// Round 11
// 240.777 us; speedup vs baseline: 1.6691x; 1.0380x over previous
//
#include <hip/hip_runtime.h>
#include <stdint.h>

#define T_STEPS 256
#define F_IN 64
#define L2E 1.44269504f

typedef __bf16 bf16x8 __attribute__((ext_vector_type(8)));
typedef float f32x4 __attribute__((ext_vector_type(4)));
typedef uint32_t u32;
typedef uint32_t u32x2 __attribute__((ext_vector_type(2)));
typedef uint32_t u32x4 __attribute__((ext_vector_type(4)));

#define GLDS16(gp, lp)                                                         \
    __builtin_amdgcn_global_load_lds(                                          \
        (const __attribute__((address_space(1))) unsigned int*)(gp),           \
        (__attribute__((address_space(3))) unsigned int*)(lp), 16, 0, 0)

static __device__ __forceinline__ u32 pk2(float lo, float hi) {
    unsigned short a = __builtin_bit_cast(unsigned short, (__bf16)lo);
    unsigned short b = __builtin_bit_cast(unsigned short, (__bf16)hi);
    return (u32)a | ((u32)b << 16);
}

// R7 (passed, 249.9us) + x-precompute pipeline: the x-part of step t+1's
// gates (8 of 12 MFMAs + all LDS x-reads/cvts) is computed during step t
// into accx[]; the per-step serial chain is only
//   ds_read h -> 1 h-MFMA (C-in = accx) -> cell -> ds_write h -> barrier.
// Numerically bit-identical to R7 (same MFMA chain, split in time).
// 2 waves per 16-row tile, unit-split; dbuf h; 1 barrier/step; stagger.
__global__ __launch_bounds__(128, 2)
void lstm_fused(const float* __restrict__ x,
                const float* __restrict__ Wl,   // [96][128]
                const float* __restrict__ bl,   // [128]
                const float* __restrict__ Wd,   // [32]
                const float* __restrict__ bd,   // [1]
                float* __restrict__ out)        // [B]
{
    __shared__ __align__(16) float  xs[4][1024];   // 16 KB x ring
    __shared__ __align__(16) __bf16 hf[2][64][8];  // h in MFMA B-frag layout, dbuf

    const int lane = threadIdx.x & 63;
    const int wid  = threadIdx.x >> 6;             // unit-half owner
    const int cl   = lane & 15;
    const int g4   = lane >> 4;
    const int rowBase = blockIdx.x * 16;

    // gate-type scale per qi (q = 2*qi+wid: qi=0 i, 1 j, 2 f, 3 o)
    const float gsc[4] = {-L2E, -2.0f * L2E, -L2E, -L2E};

    // ---- this wave's 12 pre-scaled W^T A-fragments ----
    bf16x8 wfrag[3][4];
#pragma unroll
    for (int kc = 0; kc < 3; ++kc) {
#pragma unroll
        for (int qi = 0; qi < 4; ++qi) {
            bf16x8 v;
#pragma unroll
            for (int j = 0; j < 8; ++j)
                v[j] = (__bf16)(gsc[qi] * Wl[(kc * 32 + g4 * 8 + j) * 128 + (2 * qi + wid) * 16 + cl]);
            wfrag[kc][qi] = v;
        }
    }

    // ---- pre-scaled bias as MFMA C-init ----
    f32x4 biasf[4];
#pragma unroll
    for (int qi = 0; qi < 4; ++qi) {
#pragma unroll
        for (int r = 0; r < 4; ++r) {
            const int gate = (2 * qi + wid) * 16 + g4 * 4 + r;
            biasf[qi][r] = gsc[qi] * (bl[gate] + (qi == 2 ? 1.0f : 0.0f));
        }
    }
    const float bd0 = bd[0];
    const f32x4 wdA = *(const f32x4*)(Wd + g4 * 8);
    const f32x4 wdB = *(const f32x4*)(Wd + g4 * 8 + 4);

    // per-lane pre-swizzled global base
    const float* gbase = x + (size_t)(rowBase + (lane >> 2)) * (size_t)(T_STEPS * F_IN)
                           + (size_t)(((lane & 3) ^ ((lane >> 3) & 3)) * 4);

    // h0 = 0
    if (threadIdx.x < 64)
        *reinterpret_cast<u32x4*>(&hf[0][threadIdx.x][0]) = u32x4{0u, 0u, 0u, 0u};

    // ---- phase stagger across co-resident blocks ----
    {
        const int phase = (blockIdx.x >> 8) & 3;
#pragma unroll 1
        for (int i = 0; i < phase; ++i) __builtin_amdgcn_s_sleep(10);  // ~640 cyc each
    }

    asm volatile("s_waitcnt vmcnt(0)" ::: "memory");   // drain setup loads: exact counting
    __builtin_amdgcn_sched_barrier(0);

    // prologue prefetch: slots 0..2, 2 loads/wave/slot
#pragma unroll
    for (int s = 0; s < 3; ++s) {
        const float* gp = gbase + s * F_IN + wid * 32;
        GLDS16(gp,      &xs[s][wid * 512]);
        GLDS16(gp + 16, &xs[s][wid * 512 + 256]);
    }

    asm volatile("s_waitcnt vmcnt(4) lgkmcnt(0)" ::: "memory");  // slot0 (own) + hf zeros done
    __builtin_amdgcn_sched_barrier(0);
    __builtin_amdgcn_s_barrier();
    __builtin_amdgcn_sched_barrier(0);

    const int swz = (cl >> 1) & 3;
    const int c0  = ((g4 & 1) * 2)     ^ swz;
    const int c1  = ((g4 & 1) * 2 + 1) ^ swz;
    const int kA  = (g4 >> 1) * 256 + cl * 16;
    const int kB  = kA + 512;

    // h-publish slot (R7-verified)
    const int tT = (2 * wid + (g4 >> 1)) * 16 + cl;
    const int e0 = (g4 & 1) * 4;

    float c_st[4] = {0.f, 0.f, 0.f, 0.f};   // state c' = -2*L2E*c

    // x-gate precompute for one step from its slot (8 MFMAs into accx[])
    f32x4 accx[4];
#define XGATES(SLOT) do {                                                      \
    const float* sl = &xs[SLOT][0];                                            \
    f32x4 xr0 = *(const f32x4*)(sl + kA + c0 * 4);                             \
    f32x4 xr1 = *(const f32x4*)(sl + kA + c1 * 4);                             \
    f32x4 xr2 = *(const f32x4*)(sl + kB + c0 * 4);                             \
    f32x4 xr3 = *(const f32x4*)(sl + kB + c1 * 4);                             \
    bf16x8 ax0, ax1;                                                           \
    _Pragma("unroll")                                                          \
    for (int j = 0; j < 4; ++j) {                                              \
        ax0[j]     = (__bf16)xr0[j];                                           \
        ax0[4 + j] = (__bf16)xr1[j];                                           \
        ax1[j]     = (__bf16)xr2[j];                                           \
        ax1[4 + j] = (__bf16)xr3[j];                                           \
    }                                                                          \
    _Pragma("unroll")                                                          \
    for (int qi = 0; qi < 4; ++qi) {                                           \
        f32x4 a = __builtin_amdgcn_mfma_f32_16x16x32_bf16(wfrag[0][qi], ax0, biasf[qi], 0, 0, 0); \
        accx[qi] = __builtin_amdgcn_mfma_f32_16x16x32_bf16(wfrag[1][qi], ax1, a, 0, 0, 0);        \
    }                                                                          \
} while (0)

    XGATES(0);   // accx for step 0 (slot 0 guaranteed by the vmcnt(4) above)

#define STEP(TT) do {                                                          \
    const int par = (TT) & 1;                                                  \
    /* --- critical chain: h-MFMA on precomputed x-gates, then cell --- */     \
    bf16x8 ah = *reinterpret_cast<const bf16x8*>(&hf[par][lane][0]);           \
    f32x4 acc[4];                                                              \
    __builtin_amdgcn_s_setprio(1);                                             \
    _Pragma("unroll")                                                          \
    for (int qi = 0; qi < 4; ++qi)                                             \
        acc[qi] = __builtin_amdgcn_mfma_f32_16x16x32_bf16(wfrag[2][qi], ah, accx[qi], 0, 0, 0); \
    __builtin_amdgcn_s_setprio(0);                                             \
    float hh[4];                                                               \
    _Pragma("unroll")                                                          \
    for (int r = 0; r < 4; ++r) {                                              \
        float I  = __builtin_amdgcn_exp2f(acc[0][r]);                          \
        float J  = __builtin_amdgcn_exp2f(acc[1][r]);                          \
        float Fv = __builtin_amdgcn_exp2f(acc[2][r]);                          \
        float O  = __builtin_amdgcn_exp2f(acc[3][r]);                          \
        float t3 = (1.0f + I) * (1.0f + J);                                    \
        float u  = 1.0f + Fv;                                                  \
        float np = __builtin_fmaf(J, 2.0f * L2E, -2.0f * L2E);                 \
        float r1 = __builtin_amdgcn_rcpf(t3 * u);                              \
        float num = __builtin_fmaf(c_st[r], t3, np * u);                       \
        float cp = num * r1;                                                   \
        float C  = __builtin_amdgcn_exp2f(cp);                                 \
        float r2 = __builtin_amdgcn_rcpf((1.0f + C) * (1.0f + O));             \
        hh[r] = (1.0f - C) * r2;                                               \
        c_st[r] = cp;                                                          \
    }                                                                          \
    *reinterpret_cast<u32x2*>(&hf[par ^ 1][tT][e0]) =                          \
        u32x2{pk2(hh[0], hh[1]), pk2(hh[2], hh[3])};                           \
    /* --- off-chain: stage t+3, then precompute x-gates for t+1 --- */        \
    const int tpf = ((TT) + 3 < T_STEPS) ? (TT) + 3 : T_STEPS - 1;             \
    const float* gp = gbase + tpf * F_IN + wid * 32;                           \
    GLDS16(gp,      &xs[((TT)+3) & 3][wid * 512]);                             \
    GLDS16(gp + 16, &xs[((TT)+3) & 3][wid * 512 + 256]);                       \
    asm volatile("s_waitcnt vmcnt(2)" ::: "memory");                           \
    __builtin_amdgcn_sched_barrier(0);                                         \
    const int tn = ((TT) + 1 < T_STEPS) ? (TT) + 1 : T_STEPS - 1;              \
    XGATES(tn & 3);                                                            \
    /* --- close step: publish h across waves --- */                           \
    asm volatile("s_waitcnt lgkmcnt(0)" ::: "memory");                         \
    __builtin_amdgcn_sched_barrier(0);                                         \
    __builtin_amdgcn_s_barrier();                                              \
    __builtin_amdgcn_sched_barrier(0);                                         \
} while (0)

    for (int t = 0; t < T_STEPS; t += 4) {
        STEP(t);
        STEP(t + 1);
        STEP(t + 2);
        STEP(t + 3);
    }
#undef STEP
#undef XGATES

    asm volatile("s_waitcnt vmcnt(0)" ::: "memory");   // drain tail glds

    // ---- epilogue: out[b] = ELU(sum_u h[u]*Wd[u] + bd) ----
    // T_STEPS even -> final h is in hf[0]; published by the loop's last barrier.
    if (wid == 0) {
        bf16x8 hfin = *reinterpret_cast<const bf16x8*>(&hf[0][lane][0]);
        float v = 0.f;
#pragma unroll
        for (int j = 0; j < 4; ++j) {
            v = __builtin_fmaf((float)hfin[j],     wdA[j], v);
            v = __builtin_fmaf((float)hfin[4 + j], wdB[j], v);
        }
        v += __shfl_xor(v, 16, 64);
        v += __shfl_xor(v, 32, 64);
        if (lane < 16) {
            float z = v + bd0;
            out[rowBase + lane] = z > 0.f ? z : (__expf(z) - 1.0f);
        }
    }
}

extern "C" void kernel_launch(void* const* d_in, const int* in_sizes, int n_in,
                              void* d_out, int out_size, void* d_ws, size_t ws_size,
                              hipStream_t stream) {
    const float* x  = (const float*)d_in[0];
    const float* Wl = (const float*)d_in[1];
    const float* bl = (const float*)d_in[2];
    const float* Wd = (const float*)d_in[3];
    const float* bd = (const float*)d_in[4];
    float* out = (float*)d_out;

    const int rows = out_size;              // B = 16384
    const int grid = (rows + 15) / 16;      // 16 rows per 128-thread block (2 waves/tile)
    hipLaunchKernelGGL(lstm_fused, dim3(grid), dim3(128), 0, stream,
                       x, Wl, bl, Wd, bd, out);
}

// Round 13
// 240.073 us; speedup vs baseline: 1.6740x; 1.0029x over previous
//
#include <hip/hip_runtime.h>
#include <stdint.h>

#define T_STEPS 256
#define F_IN 64
#define L2E 1.44269504f

typedef __bf16 bf16x8 __attribute__((ext_vector_type(8)));
typedef float f32x4 __attribute__((ext_vector_type(4)));
typedef uint32_t u32;
typedef uint32_t u32x4 __attribute__((ext_vector_type(4)));

#define GLDS16(gp, lp)                                                         \
    __builtin_amdgcn_global_load_lds(                                          \
        (const __attribute__((address_space(1))) unsigned int*)(gp),           \
        (__attribute__((address_space(3))) unsigned int*)(lp), 16, 0, 0)

static __device__ __forceinline__ u32 pk2(float lo, float hi) {
    unsigned short a = __builtin_bit_cast(unsigned short, (__bf16)lo);
    unsigned short b = __builtin_bit_cast(unsigned short, (__bf16)hi);
    return (u32)a | ((u32)b << 16);
}

// One wave owns one 16-row tile, all 256 steps. NO barriers, NO h-LDS.
// h exchange = R2's PROVEN select-AFTER-shuffle (8 shfl + 4 cndmask):
//   dest lane (cl,g4) needs ah[j] = h[8*g4+j][cl]; source lanes ship raw
//   packed words, dest selects with ITS OWN hi = g4>>1.
// accx pipeline (R11-proven): x-part of step t+1's gates computed during t.
// Transposed MFMA: gates^T[128][16] = (S.W^T)[128][96] @ [x|h]^T[96][16]
// A-frag: elem j of lane l -> W'[gate][k=(l>>4)*8+j]
// B-frag: elem j of lane l -> operand[k=(l>>4)*8+j][batch=l&15]
// D     : elem r of lane l -> gates'[gate=q*16+(l>>4)*4+r][batch=l&15]
__global__ __launch_bounds__(256, 1)
void lstm_fused(const float* __restrict__ x,
                const float* __restrict__ Wl,   // [96][128]
                const float* __restrict__ bl,   // [128]
                const float* __restrict__ Wd,   // [32]
                const float* __restrict__ bd,   // [1]
                float* __restrict__ out)        // [B]
{
    __shared__ __align__(16) float xs[4][4][1024];   // [wave][slot][4KB] = 64 KB

    const int lane = threadIdx.x & 63;
    const int wid  = threadIdx.x >> 6;
    const int cl   = lane & 15;
    const int g4   = lane >> 4;
    const int rowBase = blockIdx.x * 64 + wid * 16;

    // gate-type scale per tile q (q=0,1: i; 2,3: j; 4,5: f; 6,7: o)
#define GSC(q) (((q) >> 1) == 1 ? -2.0f * L2E : -L2E)

    // ---- 24 pre-scaled W^T A-fragments, ALL in standard K-row order ----
    bf16x8 wfrag[3][8];
#pragma unroll
    for (int kc = 0; kc < 3; ++kc) {
#pragma unroll
        for (int q = 0; q < 8; ++q) {
            bf16x8 v;
#pragma unroll
            for (int j = 0; j < 8; ++j)
                v[j] = (__bf16)(GSC(q) * Wl[(kc * 32 + g4 * 8 + j) * 128 + q * 16 + cl]);
            wfrag[kc][q] = v;
        }
    }

    // ---- pre-scaled bias as MFMA C-init ----
    f32x4 biasf[8];
#pragma unroll
    for (int q = 0; q < 8; ++q) {
#pragma unroll
        for (int r = 0; r < 4; ++r) {
            const int gate = q * 16 + g4 * 4 + r;
            biasf[q][r] = GSC(q) * (bl[gate] + ((q >> 1) == 2 ? 1.0f : 0.0f));
        }
    }
    const float bd0 = bd[0];
    float wdl[4], wdh[4];
#pragma unroll
    for (int r = 0; r < 4; ++r) {
        wdl[r] = Wd[4 * g4 + r];
        wdh[r] = Wd[16 + 4 * g4 + r];
    }

    // per-lane pre-swizzled global base (row = lane>>2, chunk (lane&3)^((lane>>3)&3))
    const float* gbase = x + (size_t)(rowBase + (lane >> 2)) * (size_t)(T_STEPS * F_IN)
                           + (size_t)(((lane & 3) ^ ((lane >> 3) & 3)) * 4);

    asm volatile("s_waitcnt vmcnt(0)" ::: "memory");   // drain setup loads: exact counting
    __builtin_amdgcn_sched_barrier(0);

#define STAGE(TT, SP) do {                                                     \
    const float* gp = gbase + (TT) * F_IN;                                     \
    GLDS16(gp,      &xs[wid][SP][0]);                                          \
    GLDS16(gp + 16, &xs[wid][SP][256]);                                        \
    GLDS16(gp + 32, &xs[wid][SP][512]);                                        \
    GLDS16(gp + 48, &xs[wid][SP][768]);                                        \
} while (0)

    STAGE(0, 0);
    STAGE(1, 1);
    STAGE(2, 2);

    const int swz = (cl >> 1) & 3;
    const int c0  = ((g4 & 1) * 2)     ^ swz;
    const int c1  = ((g4 & 1) * 2 + 1) ^ swz;
    const int kA  = (g4 >> 1) * 256 + cl * 16;
    const int kB  = kA + 512;

    // shuffle-exchange constants (R2-proven)
    const int srcA = cl + 32 * (g4 & 1);       // source for ah words 0,1
    const int srcB = srcA + 16;                // source for ah words 2,3
    const int sel  = g4 >> 1;                  // DEST-side word select

    f32x4 csl = {0.f, 0.f, 0.f, 0.f};   // c' = -2*L2E*c, units 4g4+r
    f32x4 csh = {0.f, 0.f, 0.f, 0.f};   // units 16+4g4+r
    f32x4 hlv, hhv;
    u32x4 ahw = {0u, 0u, 0u, 0u};       // h0 = 0
    f32x4 accx[8];

    // pointer-free LSTM cell for one unit-half (all static indices)
#define CELL(AI, AJ, AF, AO, CS, HV) do {                                      \
    _Pragma("unroll")                                                          \
    for (int r = 0; r < 4; ++r) {                                              \
        float I  = __builtin_amdgcn_exp2f((AI)[r]);                            \
        float J  = __builtin_amdgcn_exp2f((AJ)[r]);                            \
        float Fv = __builtin_amdgcn_exp2f((AF)[r]);                            \
        float O  = __builtin_amdgcn_exp2f((AO)[r]);                            \
        float t3 = (1.0f + I) * (1.0f + J);                                    \
        float uu = 1.0f + Fv;                                                  \
        float np = __builtin_fmaf(J, 2.0f * L2E, -2.0f * L2E);                 \
        float r1 = __builtin_amdgcn_rcpf(t3 * uu);                             \
        float nm = __builtin_fmaf((CS)[r], t3, np * uu);                       \
        float cp = nm * r1;                                                    \
        float C  = __builtin_amdgcn_exp2f(cp);                                 \
        float r2 = __builtin_amdgcn_rcpf((1.0f + C) * (1.0f + O));             \
        (HV)[r] = (1.0f - C) * r2;                                             \
        (CS)[r] = cp;                                                          \
    }                                                                          \
} while (0)

    // x-gate precompute for one step from its slot (8 MFMAs into accx[])
#define XGATES(SLOT) do {                                                      \
    const float* sl = &xs[wid][SLOT][0];                                       \
    f32x4 xr0 = *(const f32x4*)(sl + kA + c0 * 4);                             \
    f32x4 xr1 = *(const f32x4*)(sl + kA + c1 * 4);                             \
    f32x4 xr2 = *(const f32x4*)(sl + kB + c0 * 4);                             \
    f32x4 xr3 = *(const f32x4*)(sl + kB + c1 * 4);                             \
    bf16x8 ax0, ax1;                                                           \
    _Pragma("unroll")                                                          \
    for (int j = 0; j < 4; ++j) {                                              \
        ax0[j]     = (__bf16)xr0[j];                                           \
        ax0[4 + j] = (__bf16)xr1[j];                                           \
        ax1[j]     = (__bf16)xr2[j];                                           \
        ax1[4 + j] = (__bf16)xr3[j];                                           \
    }                                                                          \
    _Pragma("unroll")                                                          \
    for (int q = 0; q < 8; ++q) {                                              \
        f32x4 a = __builtin_amdgcn_mfma_f32_16x16x32_bf16(wfrag[0][q], ax0, biasf[q], 0, 0, 0); \
        accx[q] = __builtin_amdgcn_mfma_f32_16x16x32_bf16(wfrag[1][q], ax1, a, 0, 0, 0);        \
    }                                                                          \
} while (0)

    asm volatile("s_waitcnt vmcnt(8)" ::: "memory");   // slot 0 staged
    __builtin_amdgcn_sched_barrier(0);
    XGATES(0);

#define STEP(TT) do {                                                          \
    /* --- critical chain: h-MFMA on precomputed x-gates, then cell --- */     \
    bf16x8 ah = __builtin_bit_cast(bf16x8, ahw);                               \
    f32x4 acc[8];                                                              \
    _Pragma("unroll")                                                          \
    for (int q = 0; q < 8; ++q)                                                \
        acc[q] = __builtin_amdgcn_mfma_f32_16x16x32_bf16(wfrag[2][q], ah, accx[q], 0, 0, 0); \
    CELL(acc[0], acc[2], acc[4], acc[6], csl, hlv);                            \
    CELL(acc[1], acc[3], acc[5], acc[7], csh, hhv);                            \
    /* pack: W0=(h[4g4],h[4g4+1]) W1=(+2,+3) W2=(h[16+4g4],..) W3 */           \
    u32 W0 = pk2(hlv[0], hlv[1]);                                              \
    u32 W1 = pk2(hlv[2], hlv[3]);                                              \
    u32 W2 = pk2(hhv[0], hhv[1]);                                              \
    u32 W3 = pk2(hhv[2], hhv[3]);                                              \
    /* R2-proven: shuffle RAW words, select AFTER with dest's sel */           \
    int A0 = __shfl((int)W0, srcA, 64), A1 = __shfl((int)W1, srcA, 64);        \
    int A2 = __shfl((int)W2, srcA, 64), A3 = __shfl((int)W3, srcA, 64);        \
    int B0 = __shfl((int)W0, srcB, 64), B1 = __shfl((int)W1, srcB, 64);        \
    int B2 = __shfl((int)W2, srcB, 64), B3 = __shfl((int)W3, srcB, 64);        \
    ahw[0] = (u32)(sel ? A2 : A0);                                             \
    ahw[1] = (u32)(sel ? A3 : A1);                                             \
    ahw[2] = (u32)(sel ? B2 : B0);                                             \
    ahw[3] = (u32)(sel ? B3 : B1);                                             \
    /* --- off-chain: stage t+3, wait, precompute x-gates for t+1 --- */       \
    const int tpf = ((TT) + 3 < T_STEPS) ? (TT) + 3 : T_STEPS - 1;             \
    STAGE(tpf, ((TT) + 3) & 3);                                                \
    asm volatile("s_waitcnt vmcnt(8)" ::: "memory");                           \
    __builtin_amdgcn_sched_barrier(0);                                         \
    const int tn = ((TT) + 1 < T_STEPS) ? (TT) + 1 : T_STEPS - 1;              \
    XGATES(tn & 3);                                                            \
} while (0)

    for (int t = 0; t < T_STEPS; t += 4) {
        STEP(t);
        STEP(t + 1);
        STEP(t + 2);
        STEP(t + 3);
    }
#undef STEP
#undef XGATES
#undef CELL
#undef STAGE

    asm volatile("s_waitcnt vmcnt(0)" ::: "memory");   // drain tail glds

    // ---- epilogue: out[b] = ELU(sum_u h[u]*Wd[u] + bd) ----
    float v = 0.f;
#pragma unroll
    for (int r = 0; r < 4; ++r) {
        v = __builtin_fmaf(hlv[r], wdl[r], v);
        v = __builtin_fmaf(hhv[r], wdh[r], v);
    }
    v += __shfl_xor(v, 16, 64);
    v += __shfl_xor(v, 32, 64);
    if (lane < 16) {
        float z = v + bd0;
        out[rowBase + lane] = z > 0.f ? z : (__expf(z) - 1.0f);
    }
}

extern "C" void kernel_launch(void* const* d_in, const int* in_sizes, int n_in,
                              void* d_out, int out_size, void* d_ws, size_t ws_size,
                              hipStream_t stream) {
    const float* x  = (const float*)d_in[0];
    const float* Wl = (const float*)d_in[1];
    const float* bl = (const float*)d_in[2];
    const float* Wd = (const float*)d_in[3];
    const float* bd = (const float*)d_in[4];
    float* out = (float*)d_out;

    const int rows = out_size;              // B = 16384
    const int grid = (rows + 63) / 64;      // 64 rows per 256-thread block (4 waves x 16)
    hipLaunchKernelGGL(lstm_fused, dim3(grid), dim3(256), 0, stream,
                       x, Wl, bl, Wd, bd, out);
}